// Round 3
// baseline (449.588 us; speedup 1.0000x reference)
//
#include <hip/hip_runtime.h>

#define EPS_F 1e-5f
#define SCALE_F 0.02f

using short8  = __attribute__((ext_vector_type(8))) short;
using floatx4 = __attribute__((ext_vector_type(4))) float;

__device__ __forceinline__ unsigned short f2bf(float f) {
  unsigned u = __float_as_uint(f);
  return (unsigned short)((u + 0x7fffu + ((u >> 16) & 1u)) >> 16);
}

// async 16B global -> LDS (wave-uniform lds base + lane*16)
__device__ __forceinline__ void gl_lds16(const unsigned short* g, unsigned short* l) {
  __builtin_amdgcn_global_load_lds(
      (const __attribute__((address_space(1))) unsigned int*)g,
      (__attribute__((address_space(3))) unsigned int*)l, 16, 0, 0);
}

// ---------------- prep kernel 1: weights + BN coefficients ----------------
// ap[((off*32 + ci/8)*256 + co)*8 + ci%8] = sign(w) in bf16; bnp = fused affine
__global__ void prep_w(const float* __restrict__ w1, const float* __restrict__ w2,
                       unsigned short* __restrict__ ap1, unsigned short* __restrict__ ap2,
                       const float* g1, const float* b1, const float* m1, const float* v1,
                       const float* g2, const float* b2, const float* m2, const float* v2,
                       float* bnp) {
  int t = blockIdx.x * 256 + threadIdx.x;   // 589824 per weight tensor
  const float* __restrict__ w = blockIdx.y ? w2 : w1;
  unsigned short* __restrict__ ap = blockIdx.y ? ap2 : ap1;
  float v = w[t];
  int off = t % 9;
  int ct  = t / 9;            // co*256 + ci
  int ci  = ct & 255;
  int co  = ct >> 8;
  unsigned short b = (v > 0.f) ? 0x3F80u : ((v < 0.f) ? 0xBF80u : 0u);
  ap[((off * 32 + (ci >> 3)) * 256 + co) * 8 + (ci & 7)] = b;
  if (blockIdx.x == 0 && blockIdx.y == 0) {
    int c = threadIdx.x;
    float i1 = g1[c] * rsqrtf(v1[c] + EPS_F);
    bnp[c]       = SCALE_F * i1;
    bnp[256 + c] = b1[c] - m1[c] * i1;
    float i2 = g2[c] * rsqrtf(v2[c] + EPS_F);
    bnp[512 + c] = SCALE_F * i2;
    bnp[768 + c] = b2[c] - m2[c] * i2;
  }
}

// ---------------- prep kernel 2: x -> padded NHWC bf16 + all border zeroing ----
__global__ void prep_x(const float* __restrict__ x, unsigned short* __restrict__ xb,
                       unsigned short* __restrict__ abuf) {
  __shared__ float tile[28 * 260];   // [w][ci], pitch 260 floats
  int h = blockIdx.x;                // 0..27
  int n = blockIdx.y;
  int tid = threadIdx.x;
  const float* xs = x + ((size_t)n * 256) * 784 + h * 28;
  for (int u = tid; u < 1792; u += 256) {      // 256ci * 7 float4 along w
    int ci = u / 7;
    int j  = u - ci * 7;
    floatx4 f = *(const floatx4*)&xs[(size_t)ci * 784 + j * 4];
    tile[(j * 4 + 0) * 260 + ci] = f[0];
    tile[(j * 4 + 1) * 260 + ci] = f[1];
    tile[(j * 4 + 2) * 260 + ci] = f[2];
    tile[(j * 4 + 3) * 260 + ci] = f[3];
  }
  __syncthreads();
  unsigned short* xd = xb + ((size_t)n * 900 + (h + 1) * 30 + 1) * 256;
  for (int u = tid; u < 1792; u += 256) {      // 28px * 64 chunks(4ci)
    int w  = u >> 6;
    int c4 = u & 63;
    floatx4 f = *(const floatx4*)&tile[w * 260 + c4 * 4];
    ushort4 o;
    o.x = f2bf(f[0]); o.y = f2bf(f[1]); o.z = f2bf(f[2]); o.w = f2bf(f[3]);
    *(ushort4*)(xd + (size_t)w * 256 + c4 * 4) = o;
  }
  // side borders of padded row h+1, both buffers: 2 sides * 64 c4 * 2 bufs = 256
  {
    int bufi = tid >> 7, side = (tid >> 6) & 1, c4 = tid & 63;
    unsigned short* bb = (bufi ? abuf : xb) + ((size_t)n * 900 + (h + 1) * 30 + side * 29) * 256;
    ushort4 z = {0, 0, 0, 0};
    *(ushort4*)(bb + c4 * 4) = z;
  }
  // top/bottom padded rows
  if (h == 0 || h == 27) {
    int row = (h == 0) ? 0 : 29;
    for (int u = tid; u < 3840; u += 256) {    // 2 bufs * 30px * 64 c4
      int bufi = u / 1920;
      int r    = u - bufi * 1920;
      int px   = r >> 6, c4 = r & 63;
      unsigned short* bb = (bufi ? abuf : xb) + ((size_t)n * 900 + row * 30 + px) * 256;
      ushort4 z = {0, 0, 0, 0};
      *(ushort4*)(bb + c4 * 4) = z;
    }
  }
}

// ---------------- conv helpers ----------------
__device__ __forceinline__ void loadA4(short8* dst, const unsigned short* __restrict__ Apack,
                                       int cib, int off, int half, int quad, int coW, int l16) {
  int chunk = off * 32 + cib * 8 + half * 4 + quad;
  const unsigned short* apb = Apack + ((size_t)(chunk * 256 + coW + l16)) * 8;
#pragma unroll
  for (int c = 0; c < 4; ++c) dst[c] = *(const short8*)(apb + c * 128);
}

// LDS layout: px*64 ushorts; ci-chunk k of px stored at slot k^(px&7)
__device__ __forceinline__ void loadB7(short8* dst, const unsigned short* Bl,
                                       const int* pxS, int off, int half, int quad) {
  const int D = (off / 3) * 30 + (off % 3);
  const int C = half * 4 + quad;
#pragma unroll
  for (int s = 0; s < 7; ++s) {
    int pe  = pxS[s] + D;
    int idx = (pe << 6) + ((C ^ (pe & 7)) << 3);
    dst[s] = *(const short8*)(Bl + idx);
  }
}

// ---------------- conv (implicit GEMM, async pipelined) ----------------
// Block: 256 thr = 4 waves, 256co x 112sp (4 rows) of one image.
// ci-block 64: LDS halo 6 rows x 30 px (192-px padded), double-buffered,
// staged with swizzled global_load_lds; 1 barrier per ci-block.
template<int STAGE>
__global__ __launch_bounds__(256, 2) void bconv(
    const unsigned short* __restrict__ Bin,
    const unsigned short* __restrict__ Apack,
    const float* __restrict__ bnp,
    unsigned short* __restrict__ aout,
    const float* __restrict__ xres,
    float* __restrict__ out)
{
  __shared__ __align__(16) unsigned short Blds[2][192 * 64];

  const int tid  = threadIdx.x;
  const int lane = tid & 63;
  const int wv   = tid >> 6;
  const int quad = lane >> 4;
  const int l16  = lane & 15;
  const int spBlk = blockIdx.x;   // 0..6
  const int n     = blockIdx.y;

  const int prow0 = 4 * spBlk;
  const unsigned short* bsrc = Bin + ((size_t)n * 900 + prow0 * 30) * 256;
  const int coW = wv * 64;

  int pxS[7];
#pragma unroll
  for (int s = 0; s < 7; ++s) {
    int lm = s * 16 + l16;
    int hl = lm / 28;
    int w  = lm - hl * 28;
    pxS[s] = hl * 30 + w;
  }

  const int sl_px = lane >> 3;                 // px within 8-px group
  const int sl_ch = (lane & 7) ^ sl_px;        // swizzled ci-chunk to fetch

  floatx4 acc[4][7];
#pragma unroll
  for (int c = 0; c < 4; ++c)
#pragma unroll
    for (int s = 0; s < 7; ++s)
      acc[c][s] = (floatx4){0.f, 0.f, 0.f, 0.f};

  // stage ci-block 0 into buf 0 (async), prefetch first A frags
  short8 Af[2][4], Bf[2][7];
  loadA4(Af[0], Apack, 0, 0, 0, quad, coW, l16);
#pragma unroll
  for (int i = 0; i < 6; ++i) {
    int px0 = wv * 48 + i * 8;
    int px = px0 + sl_px; px = px > 179 ? 179 : px;
    gl_lds16(bsrc + (size_t)px * 256 + sl_ch * 8, &Blds[0][px0 * 64]);
  }
  __syncthreads();

  int cur = 0;
#pragma unroll 1
  for (int cib = 0; cib < 4; ++cib) {
    const unsigned short* Bl = &Blds[cur][0];
    loadB7(Bf[0], Bl, pxS, 0, 0, quad);
#pragma unroll
    for (int st = 0; st < 18; ++st) {
      const int cu = st & 1, nx = cu ^ 1;
      if (st < 17) {
        const int o2 = (st + 1) >> 1, h2 = (st + 1) & 1;
        loadA4(Af[nx], Apack, cib, o2, h2, quad, coW, l16);
        loadB7(Bf[nx], Bl, pxS, o2, h2, quad);
      }
      if (st == 8 && cib < 3) {   // after this step's loads: ~2 steps of MFMA cover
        const int ci0 = (cib + 1) * 64;
        unsigned short* dbuf = &Blds[cur ^ 1][0];
#pragma unroll
        for (int i = 0; i < 6; ++i) {
          int px0 = wv * 48 + i * 8;
          int px = px0 + sl_px; px = px > 179 ? 179 : px;
          gl_lds16(bsrc + (size_t)px * 256 + ci0 + sl_ch * 8, dbuf + px0 * 64);
        }
      }
      if (st == 17 && cib < 3) {  // cross-barrier A prefetch (drained by barrier)
        loadA4(Af[nx], Apack, cib + 1, 0, 0, quad, coW, l16);
      }
#pragma unroll
      for (int s = 0; s < 7; ++s)
#pragma unroll
        for (int c = 0; c < 4; ++c)
          acc[c][s] = __builtin_amdgcn_mfma_f32_16x16x32_bf16(Af[cu][c], Bf[cu][s], acc[c][s], 0, 0, 0);
    }
    __syncthreads();
    cur ^= 1;
  }

  // Epilogue. C/D layout: col(sp)=l16, row(co within 16-tile)=quad*4+reg.
  if (STAGE == 1) {
#pragma unroll
    for (int c = 0; c < 4; ++c) {
      int co = coW + c * 16 + quad * 4;
      floatx4 As = *(const floatx4*)(bnp + co);
      floatx4 Bs = *(const floatx4*)(bnp + 256 + co);
#pragma unroll
      for (int s = 0; s < 7; ++s) {
        int lm = s * 16 + l16;
        int hl = lm / 28;
        int w  = lm - hl * 28;
        int pix = (prow0 + hl + 1) * 30 + w + 1;
        unsigned short* dst = aout + ((size_t)n * 900 + pix) * 256 + co;
        ushort4 o;
        o.x = f2bf(fmaxf(acc[c][s][0] * As[0] + Bs[0], 0.f));
        o.y = f2bf(fmaxf(acc[c][s][1] * As[1] + Bs[1], 0.f));
        o.z = f2bf(fmaxf(acc[c][s][2] * As[2] + Bs[2], 0.f));
        o.w = f2bf(fmaxf(acc[c][s][3] * As[3] + Bs[3], 0.f));
        *(ushort4*)dst = o;
      }
    }
  } else {
#pragma unroll
    for (int c = 0; c < 4; ++c) {
      int co = coW + c * 16 + quad * 4;
      floatx4 As = *(const floatx4*)(bnp + 512 + co);
      floatx4 Bs = *(const floatx4*)(bnp + 768 + co);
#pragma unroll
      for (int s = 0; s < 7; ++s) {
        int m = spBlk * 112 + s * 16 + l16;
#pragma unroll
        for (int r = 0; r < 4; ++r) {
          size_t oidx = ((size_t)n * 256 + co + r) * 784 + m;
          float v = acc[c][s][r] * As[r] + Bs[r] + xres[oidx];
          out[oidx] = fmaxf(v, 0.f);
        }
      }
    }
  }
}

// ---------------- launch ----------------

extern "C" void kernel_launch(void* const* d_in, const int* in_sizes, int n_in,
                              void* d_out, int out_size, void* d_ws, size_t ws_size,
                              hipStream_t stream) {
  const float* x  = (const float*)d_in[0];
  const float* w1 = (const float*)d_in[1];
  const float* g1 = (const float*)d_in[2];
  const float* b1 = (const float*)d_in[3];
  const float* m1 = (const float*)d_in[4];
  const float* v1 = (const float*)d_in[5];
  const float* w2 = (const float*)d_in[6];
  const float* g2 = (const float*)d_in[7];
  const float* b2 = (const float*)d_in[8];
  const float* m2 = (const float*)d_in[9];
  const float* v2 = (const float*)d_in[10];
  float* out = (float*)d_out;

  char* ws = (char*)d_ws;
  const size_t PADBUF = (size_t)64 * 900 * 256 * 2;   // 29,491,200 B
  const size_t WPACK  = 589824ull * 2;                 // 1,179,648 B
  unsigned short* xb   = (unsigned short*)ws;
  unsigned short* abuf = (unsigned short*)(ws + PADBUF);
  unsigned short* ap1  = (unsigned short*)(ws + 2 * PADBUF);
  unsigned short* ap2  = (unsigned short*)(ws + 2 * PADBUF + WPACK);
  float* bnp           = (float*)(ws + 2 * PADBUF + 2 * WPACK);

  prep_w<<<dim3(2304, 2), 256, 0, stream>>>(w1, w2, ap1, ap2,
                                            g1, b1, m1, v1, g2, b2, m2, v2, bnp);
  prep_x<<<dim3(28, 64), 256, 0, stream>>>(x, xb, abuf);

  dim3 grid(7, 64);   // sp-tile, image
  bconv<1><<<grid, 256, 0, stream>>>(xb,   ap1, bnp, abuf, nullptr, nullptr);
  bconv<2><<<grid, 256, 0, stream>>>(abuf, ap2, bnp, nullptr, x, out);
}

// Round 4
// 420.627 us; speedup vs baseline: 1.0689x; 1.0689x over previous
//
#include <hip/hip_runtime.h>

#define EPS_F 1e-5f
#define SCALE_F 0.02f

using short8  = __attribute__((ext_vector_type(8))) short;
using floatx4 = __attribute__((ext_vector_type(4))) float;

__device__ __forceinline__ unsigned short f2bf(float f) {
  unsigned u = __float_as_uint(f);
  return (unsigned short)((u + 0x7fffu + ((u >> 16) & 1u)) >> 16);
}

// ---------------- prep kernel 1: weights + BN coefficients ----------------
// ap[((off*32 + ci/8)*256 + co)*8 + ci%8] = sign(w) in bf16; bnp = fused affine
__global__ void prep_w(const float* __restrict__ w1, const float* __restrict__ w2,
                       unsigned short* __restrict__ ap1, unsigned short* __restrict__ ap2,
                       const float* g1, const float* b1, const float* m1, const float* v1,
                       const float* g2, const float* b2, const float* m2, const float* v2,
                       float* bnp) {
  int t = blockIdx.x * 256 + threadIdx.x;   // 589824 per weight tensor
  const float* __restrict__ w = blockIdx.y ? w2 : w1;
  unsigned short* __restrict__ ap = blockIdx.y ? ap2 : ap1;
  float v = w[t];
  int off = t % 9;
  int ct  = t / 9;            // co*256 + ci
  int ci  = ct & 255;
  int co  = ct >> 8;
  unsigned short b = (v > 0.f) ? 0x3F80u : ((v < 0.f) ? 0xBF80u : 0u);
  ap[((off * 32 + (ci >> 3)) * 256 + co) * 8 + (ci & 7)] = b;
  if (blockIdx.x == 0 && blockIdx.y == 0) {
    int c = threadIdx.x;
    float i1 = g1[c] * rsqrtf(v1[c] + EPS_F);
    bnp[c]       = SCALE_F * i1;
    bnp[256 + c] = b1[c] - m1[c] * i1;
    float i2 = g2[c] * rsqrtf(v2[c] + EPS_F);
    bnp[512 + c] = SCALE_F * i2;
    bnp[768 + c] = b2[c] - m2[c] * i2;
  }
}

// ---------------- prep kernel 2: x -> padded NHWC bf16 + all border zeroing ----
__global__ void prep_x(const float* __restrict__ x, unsigned short* __restrict__ xb,
                       unsigned short* __restrict__ abuf) {
  __shared__ float tile[28 * 260];   // [w][ci], pitch 260 floats
  int h = blockIdx.x;                // 0..27
  int n = blockIdx.y;
  int tid = threadIdx.x;
  const float* xs = x + ((size_t)n * 256) * 784 + h * 28;
  for (int u = tid; u < 1792; u += 256) {      // 256ci * 7 float4 along w
    int ci = u / 7;
    int j  = u - ci * 7;
    floatx4 f = *(const floatx4*)&xs[(size_t)ci * 784 + j * 4];
    tile[(j * 4 + 0) * 260 + ci] = f[0];
    tile[(j * 4 + 1) * 260 + ci] = f[1];
    tile[(j * 4 + 2) * 260 + ci] = f[2];
    tile[(j * 4 + 3) * 260 + ci] = f[3];
  }
  __syncthreads();
  unsigned short* xd = xb + ((size_t)n * 900 + (h + 1) * 30 + 1) * 256;
  for (int u = tid; u < 1792; u += 256) {      // 28px * 64 chunks(4ci)
    int w  = u >> 6;
    int c4 = u & 63;
    floatx4 f = *(const floatx4*)&tile[w * 260 + c4 * 4];
    ushort4 o;
    o.x = f2bf(f[0]); o.y = f2bf(f[1]); o.z = f2bf(f[2]); o.w = f2bf(f[3]);
    *(ushort4*)(xd + (size_t)w * 256 + c4 * 4) = o;
  }
  // side borders of padded row h+1, both buffers: 2 sides * 64 c4 * 2 bufs = 256
  {
    int bufi = tid >> 7, side = (tid >> 6) & 1, c4 = tid & 63;
    unsigned short* bb = (bufi ? abuf : xb) + ((size_t)n * 900 + (h + 1) * 30 + side * 29) * 256;
    ushort4 z = {0, 0, 0, 0};
    *(ushort4*)(bb + c4 * 4) = z;
  }
  // top/bottom padded rows
  if (h == 0 || h == 27) {
    int row = (h == 0) ? 0 : 29;
    for (int u = tid; u < 3840; u += 256) {    // 2 bufs * 30px * 64 c4
      int bufi = u / 1920;
      int r    = u - bufi * 1920;
      int px   = r >> 6, c4 = r & 63;
      unsigned short* bb = (bufi ? abuf : xb) + ((size_t)n * 900 + row * 30 + px) * 256;
      ushort4 z = {0, 0, 0, 0};
      *(ushort4*)(bb + c4 * 4) = z;
    }
  }
}

// ---------------- conv helpers ----------------
__device__ __forceinline__ void loadA4(short8* dst, const unsigned short* __restrict__ Apack,
                                       int cib, int off, int half, int quad, int coW, int l16) {
  int chunk = off * 32 + cib * 8 + half * 4 + quad;
  const unsigned short* apb = Apack + ((size_t)(chunk * 256 + coW + l16)) * 8;
#pragma unroll
  for (int c = 0; c < 4; ++c) dst[c] = *(const short8*)(apb + c * 128);
}

// LDS layout: px*64 ushorts; ci-chunk k of px stored at slot k^(px&7)
__device__ __forceinline__ void loadB7(short8* dst, const unsigned short* Bl,
                                       const int* pxS, int off, int half, int quad) {
  const int D = (off / 3) * 30 + (off % 3);
  const int C = half * 4 + quad;
#pragma unroll
  for (int s = 0; s < 7; ++s) {
    int pe  = pxS[s] + D;
    int idx = (pe << 6) + ((C ^ (pe & 7)) << 3);
    dst[s] = *(const short8*)(Bl + idx);
  }
}

// ---------------- conv (implicit GEMM, register-carried async staging) ----------
// Block: 256 thr = 4 waves, 256co x 112sp (4 rows) of one image.
// ci-block 64: LDS halo 6 rows x 30 px, XOR-swizzled pitch-64; staging loads
// issued into registers at st==12 of the previous ci-block (~2500 cyc cover),
// stored to LDS at the barrier. A-frags double-buffered w/ cross-barrier prefetch.
template<int STAGE>
__global__ __launch_bounds__(256, 2) void bconv(
    const unsigned short* __restrict__ Bin,
    const unsigned short* __restrict__ Apack,
    const float* __restrict__ bnp,
    unsigned short* __restrict__ aout,
    const float* __restrict__ xres,
    float* __restrict__ out)
{
  __shared__ __align__(16) unsigned short Blds[180 * 64];

  const int tid  = threadIdx.x;
  const int lane = tid & 63;
  const int wv   = tid >> 6;
  const int quad = lane >> 4;
  const int l16  = lane & 15;
  const int spBlk = blockIdx.x;   // 0..6
  const int n     = blockIdx.y;

  const int prow0 = 4 * spBlk;
  const unsigned short* bsrc = Bin + ((size_t)n * 900 + prow0 * 30) * 256;
  const int coW = wv * 64;

  int pxS[7];
#pragma unroll
  for (int s = 0; s < 7; ++s) {
    int lm = s * 16 + l16;
    int hl = lm / 28;
    int w  = lm - hl * 28;
    pxS[s] = hl * 30 + w;
  }

  // staging: 1440 b128 units (180 px x 8 ci-chunks); thread k-th unit clamped
  int gofs[6], lofs[6];
#pragma unroll
  for (int k = 0; k < 6; ++k) {
    int u = tid + k * 256;
    u = (u < 1440) ? u : 1439;         // dup stores write identical data: benign
    int px = u >> 3, c = u & 7;
    gofs[k] = px * 256 + c * 8;
    lofs[k] = (px << 6) + ((c ^ (px & 7)) << 3);
  }

  floatx4 acc[4][7];
#pragma unroll
  for (int c = 0; c < 4; ++c)
#pragma unroll
    for (int s = 0; s < 7; ++s)
      acc[c][s] = (floatx4){0.f, 0.f, 0.f, 0.f};

  short8 Sreg[6];
  short8 Af[2][4];

  // prologue: stage ci-block 0, prefetch first A
  loadA4(Af[0], Apack, 0, 0, 0, quad, coW, l16);
#pragma unroll
  for (int k = 0; k < 6; ++k) Sreg[k] = *(const short8*)(bsrc + gofs[k]);
#pragma unroll
  for (int k = 0; k < 6; ++k) *(short8*)&Blds[lofs[k]] = Sreg[k];
  __syncthreads();

#pragma unroll 1
  for (int cib = 0; cib < 4; ++cib) {
#pragma unroll
    for (int st = 0; st < 18; ++st) {
      const int cu = st & 1, nx = cu ^ 1;
      short8 Bf[7];
      loadB7(Bf, Blds, pxS, st >> 1, st & 1, quad);
      if (st < 17)
        loadA4(Af[nx], Apack, cib, (st + 1) >> 1, (st + 1) & 1, quad, coW, l16);
      if (st == 12 && cib < 3) {      // issue next ci-block staging into registers
        const int co_ofs = (cib + 1) * 64;
#pragma unroll
        for (int k = 0; k < 6; ++k)
          Sreg[k] = *(const short8*)(bsrc + gofs[k] + co_ofs);
      }
      if (st == 17 && cib < 3)        // cross-barrier A prefetch for next cib
        loadA4(Af[nx], Apack, cib + 1, 0, 0, quad, coW, l16);
#pragma unroll
      for (int s = 0; s < 7; ++s)
#pragma unroll
        for (int c = 0; c < 4; ++c)
          acc[c][s] = __builtin_amdgcn_mfma_f32_16x16x32_bf16(Af[cu][c], Bf[s], acc[c][s], 0, 0, 0);
    }
    if (cib < 3) {
      __syncthreads();                 // all reads of Blds done
#pragma unroll
      for (int k = 0; k < 6; ++k) *(short8*)&Blds[lofs[k]] = Sreg[k];
      __syncthreads();
    }
  }

  // Epilogue. C/D layout: col(sp)=l16, row(co within 16-tile)=quad*4+reg.
  if (STAGE == 1) {
#pragma unroll
    for (int c = 0; c < 4; ++c) {
      int co = coW + c * 16 + quad * 4;
      floatx4 As = *(const floatx4*)(bnp + co);
      floatx4 Bs = *(const floatx4*)(bnp + 256 + co);
#pragma unroll
      for (int s = 0; s < 7; ++s) {
        int lm = s * 16 + l16;
        int hl = lm / 28;
        int w  = lm - hl * 28;
        int pix = (prow0 + hl + 1) * 30 + w + 1;
        unsigned short* dst = aout + ((size_t)n * 900 + pix) * 256 + co;
        ushort4 o;
        o.x = f2bf(fmaxf(acc[c][s][0] * As[0] + Bs[0], 0.f));
        o.y = f2bf(fmaxf(acc[c][s][1] * As[1] + Bs[1], 0.f));
        o.z = f2bf(fmaxf(acc[c][s][2] * As[2] + Bs[2], 0.f));
        o.w = f2bf(fmaxf(acc[c][s][3] * As[3] + Bs[3], 0.f));
        *(ushort4*)dst = o;
      }
    }
  } else {
#pragma unroll
    for (int c = 0; c < 4; ++c) {
      int co = coW + c * 16 + quad * 4;
      floatx4 As = *(const floatx4*)(bnp + 512 + co);
      floatx4 Bs = *(const floatx4*)(bnp + 768 + co);
#pragma unroll
      for (int s = 0; s < 7; ++s) {
        int m = spBlk * 112 + s * 16 + l16;
#pragma unroll
        for (int r = 0; r < 4; ++r) {
          size_t oidx = ((size_t)n * 256 + co + r) * 784 + m;
          float v = acc[c][s][r] * As[r] + Bs[r] + xres[oidx];
          out[oidx] = fmaxf(v, 0.f);
        }
      }
    }
  }
}

// ---------------- launch ----------------

extern "C" void kernel_launch(void* const* d_in, const int* in_sizes, int n_in,
                              void* d_out, int out_size, void* d_ws, size_t ws_size,
                              hipStream_t stream) {
  const float* x  = (const float*)d_in[0];
  const float* w1 = (const float*)d_in[1];
  const float* g1 = (const float*)d_in[2];
  const float* b1 = (const float*)d_in[3];
  const float* m1 = (const float*)d_in[4];
  const float* v1 = (const float*)d_in[5];
  const float* w2 = (const float*)d_in[6];
  const float* g2 = (const float*)d_in[7];
  const float* b2 = (const float*)d_in[8];
  const float* m2 = (const float*)d_in[9];
  const float* v2 = (const float*)d_in[10];
  float* out = (float*)d_out;

  char* ws = (char*)d_ws;
  const size_t PADBUF = (size_t)64 * 900 * 256 * 2;   // 29,491,200 B
  const size_t WPACK  = 589824ull * 2;                 // 1,179,648 B
  unsigned short* xb   = (unsigned short*)ws;
  unsigned short* abuf = (unsigned short*)(ws + PADBUF);
  unsigned short* ap1  = (unsigned short*)(ws + 2 * PADBUF);
  unsigned short* ap2  = (unsigned short*)(ws + 2 * PADBUF + WPACK);
  float* bnp           = (float*)(ws + 2 * PADBUF + 2 * WPACK);

  prep_w<<<dim3(2304, 2), 256, 0, stream>>>(w1, w2, ap1, ap2,
                                            g1, b1, m1, v1, g2, b2, m2, v2, bnp);
  prep_x<<<dim3(28, 64), 256, 0, stream>>>(x, xb, abuf);

  dim3 grid(7, 64);   // sp-tile, image
  bconv<1><<<grid, 256, 0, stream>>>(xb,   ap1, bnp, abuf, nullptr, nullptr);
  bconv<2><<<grid, 256, 0, stream>>>(abuf, ap2, bnp, nullptr, x, out);
}

// Round 5
// 263.990 us; speedup vs baseline: 1.7031x; 1.5933x over previous
//
#include <hip/hip_runtime.h>

#define EPS_F 1e-5f
#define SCALE_F 0.02f

using short8  = __attribute__((ext_vector_type(8))) short;
using floatx4 = __attribute__((ext_vector_type(4))) float;

__device__ __forceinline__ unsigned short f2bf(float f) {
  unsigned u = __float_as_uint(f);
  return (unsigned short)((u + 0x7fffu + ((u >> 16) & 1u)) >> 16);
}

// ---------------- prep kernel 1: weights + BN coefficients ----------------
// Gather form: 1 thread = one 16B output group (off, c8, co) -> 8 bf16 signs.
// ap[((off*32 + c8)*256 + co)*8 + j] = sign(w[(co*256 + c8*8 + j)*9 + off])
// Reads are scattered 4B (w is 2.25 MB -> L2-resident); stores fully coalesced.
__global__ void prep_w(const float* __restrict__ w1, const float* __restrict__ w2,
                       unsigned short* __restrict__ ap1, unsigned short* __restrict__ ap2,
                       const float* g1, const float* b1, const float* m1, const float* v1,
                       const float* g2, const float* b2, const float* m2, const float* v2,
                       float* bnp) {
  const float* __restrict__ w = blockIdx.y ? w2 : w1;
  unsigned short* __restrict__ ap = blockIdx.y ? ap2 : ap1;
  int t = blockIdx.x * 256 + threadIdx.x;   // 73728 groups per tensor
  int off = t >> 13;
  int c8  = (t >> 8) & 31;
  int co  = t & 255;
  const float* ws = w + (size_t)(co * 256 + c8 * 8) * 9 + off;
  short8 o;
#pragma unroll
  for (int j = 0; j < 8; ++j) {
    float v = ws[j * 9];
    o[j] = (v > 0.f) ? (short)0x3F80 : ((v < 0.f) ? (short)0xBF80 : (short)0);
  }
  *(short8*)(ap + (size_t)t * 8) = o;
  if (blockIdx.x == 0 && blockIdx.y == 0) {
    int c = threadIdx.x;
    float i1 = g1[c] * rsqrtf(v1[c] + EPS_F);
    bnp[c]       = SCALE_F * i1;
    bnp[256 + c] = b1[c] - m1[c] * i1;
    float i2 = g2[c] * rsqrtf(v2[c] + EPS_F);
    bnp[512 + c] = SCALE_F * i2;
    bnp[768 + c] = b2[c] - m2[c] * i2;
  }
}

// ---------------- prep kernel 2: x -> padded NHWC bf16 + all border zeroing ----
__global__ void prep_x(const float* __restrict__ x, unsigned short* __restrict__ xb,
                       unsigned short* __restrict__ abuf) {
  __shared__ float tile[28 * 260];   // [w][ci], pitch 260 floats
  int h = blockIdx.x;                // 0..27
  int n = blockIdx.y;
  int tid = threadIdx.x;
  const float* xs = x + ((size_t)n * 256) * 784 + h * 28;
  for (int u = tid; u < 1792; u += 256) {      // 256ci * 7 float4 along w
    int ci = u / 7;
    int j  = u - ci * 7;
    floatx4 f = *(const floatx4*)&xs[(size_t)ci * 784 + j * 4];
    tile[(j * 4 + 0) * 260 + ci] = f[0];
    tile[(j * 4 + 1) * 260 + ci] = f[1];
    tile[(j * 4 + 2) * 260 + ci] = f[2];
    tile[(j * 4 + 3) * 260 + ci] = f[3];
  }
  __syncthreads();
  unsigned short* xd = xb + ((size_t)n * 900 + (h + 1) * 30 + 1) * 256;
  for (int u = tid; u < 1792; u += 256) {      // 28px * 64 chunks(4ci)
    int w  = u >> 6;
    int c4 = u & 63;
    floatx4 f = *(const floatx4*)&tile[w * 260 + c4 * 4];
    ushort4 o;
    o.x = f2bf(f[0]); o.y = f2bf(f[1]); o.z = f2bf(f[2]); o.w = f2bf(f[3]);
    *(ushort4*)(xd + (size_t)w * 256 + c4 * 4) = o;
  }
  // side borders of padded row h+1, both buffers: 2 sides * 64 c4 * 2 bufs = 256
  {
    int bufi = tid >> 7, side = (tid >> 6) & 1, c4 = tid & 63;
    unsigned short* bb = (bufi ? abuf : xb) + ((size_t)n * 900 + (h + 1) * 30 + side * 29) * 256;
    ushort4 z = {0, 0, 0, 0};
    *(ushort4*)(bb + c4 * 4) = z;
  }
  // top/bottom padded rows
  if (h == 0 || h == 27) {
    int row = (h == 0) ? 0 : 29;
    for (int u = tid; u < 3840; u += 256) {    // 2 bufs * 30px * 64 c4
      int bufi = u / 1920;
      int r    = u - bufi * 1920;
      int px   = r >> 6, c4 = r & 63;
      unsigned short* bb = (bufi ? abuf : xb) + ((size_t)n * 900 + row * 30 + px) * 256;
      ushort4 z = {0, 0, 0, 0};
      *(ushort4*)(bb + c4 * 4) = z;
    }
  }
}

// ---------------- conv (implicit GEMM, halo-tiled; round-2 structure) ----------
// Block: 256 thr = 4 waves. Macro-tile: 256 co x 112 sp (4 rows) of one image.
// Wave wv: co [wv*64, +64), all 112 sp -> acc 4x7 floatx4 (AGPRs).
// ci-block 64: LDS halo 6 rows x 30 px, XOR-swizzled pitch-64
// (ci-chunk c of px stored at slot c^(px&7)); 2 barriers per ci-block.
template<int STAGE>
__global__ __launch_bounds__(256, 2) void bconv(
    const unsigned short* __restrict__ Bin,
    const unsigned short* __restrict__ Apack,
    const float* __restrict__ bnp,
    unsigned short* __restrict__ aout,
    const float* __restrict__ xres,
    float* __restrict__ out)
{
  __shared__ __align__(16) unsigned short Blds[180 * 64];

  const int tid  = threadIdx.x;
  const int lane = tid & 63;
  const int wv   = tid >> 6;
  const int quad = lane >> 4;
  const int l16  = lane & 15;
  const int spBlk = blockIdx.x;   // 0..6
  const int n     = blockIdx.y;

  const int prow0 = 4 * spBlk;
  const unsigned short* bsrc = Bin + ((size_t)n * 900 + prow0 * 30) * 256;
  const int coW = wv * 64;

  int pxS[7];
#pragma unroll
  for (int s = 0; s < 7; ++s) {
    int lm = s * 16 + l16;
    int hl = lm / 28;
    int w  = lm - hl * 28;
    pxS[s] = hl * 30 + w;
  }

  floatx4 acc[4][7];
#pragma unroll
  for (int c = 0; c < 4; ++c)
#pragma unroll
    for (int s = 0; s < 7; ++s)
      acc[c][s] = (floatx4){0.f, 0.f, 0.f, 0.f};

#pragma unroll 1
  for (int cb = 0; cb < 4; ++cb) {
    __syncthreads();   // previous ci-block's frag reads complete
    // stage 180 px x 64 ci (1440 x 16B units), swizzled
    for (int u = tid; u < 1440; u += 256) {
      int px = u >> 3, c = u & 7;
      const unsigned short* src = bsrc + (size_t)px * 256 + cb * 64 + c * 8;
      *(short8*)&Blds[(px << 6) + ((c ^ (px & 7)) << 3)] = *(const short8*)src;
    }
    __syncthreads();

    const int cq = cb * 8 + quad;
#pragma unroll 1
    for (int kh = 0; kh < 3; ++kh) {
#pragma unroll 1
      for (int kw = 0; kw < 3; ++kw) {
        const int D = kh * 30 + kw;
        const int chunk0 = (kh * 3 + kw) * 32 + cq;
#pragma unroll
        for (int half = 0; half < 2; ++half) {
          const int chunk = chunk0 + half * 4;
          const unsigned short* apb = Apack + ((size_t)(chunk * 256 + coW + l16)) * 8;
          short8 a0 = *(const short8*)(apb);
          short8 a1 = *(const short8*)(apb + 16 * 8);
          short8 a2 = *(const short8*)(apb + 32 * 8);
          short8 a3 = *(const short8*)(apb + 48 * 8);
          const int C = half * 4 + quad;
#pragma unroll
          for (int s = 0; s < 7; ++s) {
            int pe = pxS[s] + D;
            short8 b = *(const short8*)&Blds[(pe << 6) + ((C ^ (pe & 7)) << 3)];
            acc[0][s] = __builtin_amdgcn_mfma_f32_16x16x32_bf16(a0, b, acc[0][s], 0, 0, 0);
            acc[1][s] = __builtin_amdgcn_mfma_f32_16x16x32_bf16(a1, b, acc[1][s], 0, 0, 0);
            acc[2][s] = __builtin_amdgcn_mfma_f32_16x16x32_bf16(a2, b, acc[2][s], 0, 0, 0);
            acc[3][s] = __builtin_amdgcn_mfma_f32_16x16x32_bf16(a3, b, acc[3][s], 0, 0, 0);
          }
        }
      }
    }
  }

  // Epilogue. C/D layout: col(sp)=l16, row(co within 16-tile)=quad*4+reg.
  if (STAGE == 1) {
#pragma unroll
    for (int c = 0; c < 4; ++c) {
      int co = coW + c * 16 + quad * 4;
      floatx4 As = *(const floatx4*)(bnp + co);
      floatx4 Bs = *(const floatx4*)(bnp + 256 + co);
#pragma unroll
      for (int s = 0; s < 7; ++s) {
        int lm = s * 16 + l16;
        int hl = lm / 28;
        int w  = lm - hl * 28;
        int pix = (prow0 + hl + 1) * 30 + w + 1;
        unsigned short* dst = aout + ((size_t)n * 900 + pix) * 256 + co;
        ushort4 o;
        o.x = f2bf(fmaxf(acc[c][s][0] * As[0] + Bs[0], 0.f));
        o.y = f2bf(fmaxf(acc[c][s][1] * As[1] + Bs[1], 0.f));
        o.z = f2bf(fmaxf(acc[c][s][2] * As[2] + Bs[2], 0.f));
        o.w = f2bf(fmaxf(acc[c][s][3] * As[3] + Bs[3], 0.f));
        *(ushort4*)dst = o;
      }
    }
  } else {
#pragma unroll
    for (int c = 0; c < 4; ++c) {
      int co = coW + c * 16 + quad * 4;
      floatx4 As = *(const floatx4*)(bnp + 512 + co);
      floatx4 Bs = *(const floatx4*)(bnp + 768 + co);
#pragma unroll
      for (int s = 0; s < 7; ++s) {
        int m = spBlk * 112 + s * 16 + l16;
#pragma unroll
        for (int r = 0; r < 4; ++r) {
          size_t oidx = ((size_t)n * 256 + co + r) * 784 + m;
          float v = acc[c][s][r] * As[r] + Bs[r] + xres[oidx];
          out[oidx] = fmaxf(v, 0.f);
        }
      }
    }
  }
}

// ---------------- launch ----------------

extern "C" void kernel_launch(void* const* d_in, const int* in_sizes, int n_in,
                              void* d_out, int out_size, void* d_ws, size_t ws_size,
                              hipStream_t stream) {
  const float* x  = (const float*)d_in[0];
  const float* w1 = (const float*)d_in[1];
  const float* g1 = (const float*)d_in[2];
  const float* b1 = (const float*)d_in[3];
  const float* m1 = (const float*)d_in[4];
  const float* v1 = (const float*)d_in[5];
  const float* w2 = (const float*)d_in[6];
  const float* g2 = (const float*)d_in[7];
  const float* b2 = (const float*)d_in[8];
  const float* m2 = (const float*)d_in[9];
  const float* v2 = (const float*)d_in[10];
  float* out = (float*)d_out;

  char* ws = (char*)d_ws;
  const size_t PADBUF = (size_t)64 * 900 * 256 * 2;   // 29,491,200 B
  const size_t WPACK  = 589824ull * 2;                 // 1,179,648 B
  unsigned short* xb   = (unsigned short*)ws;
  unsigned short* abuf = (unsigned short*)(ws + PADBUF);
  unsigned short* ap1  = (unsigned short*)(ws + 2 * PADBUF);
  unsigned short* ap2  = (unsigned short*)(ws + 2 * PADBUF + WPACK);
  float* bnp           = (float*)(ws + 2 * PADBUF + 2 * WPACK);

  prep_w<<<dim3(288, 2), 256, 0, stream>>>(w1, w2, ap1, ap2,
                                           g1, b1, m1, v1, g2, b2, m2, v2, bnp);
  prep_x<<<dim3(28, 64), 256, 0, stream>>>(x, xb, abuf);

  dim3 grid(7, 64);   // sp-tile, image
  bconv<1><<<grid, 256, 0, stream>>>(xb,   ap1, bnp, abuf, nullptr, nullptr);
  bconv<2><<<grid, 256, 0, stream>>>(abuf, ap2, bnp, nullptr, x, out);
}

// Round 6
// 252.135 us; speedup vs baseline: 1.7831x; 1.0470x over previous
//
#include <hip/hip_runtime.h>

#define EPS_F 1e-5f
#define SCALE_F 0.02f

using short8  = __attribute__((ext_vector_type(8))) short;
using floatx4 = __attribute__((ext_vector_type(4))) float;

__device__ __forceinline__ unsigned short f2bf(float f) {
  unsigned u = __float_as_uint(f);
  return (unsigned short)((u + 0x7fffu + ((u >> 16) & 1u)) >> 16);
}

// ---------------- prep kernel 1: weights + BN coefficients ----------------
// Gather form: 1 thread = one 16B output group (off, c8, co) -> 8 bf16 signs.
__global__ void prep_w(const float* __restrict__ w1, const float* __restrict__ w2,
                       unsigned short* __restrict__ ap1, unsigned short* __restrict__ ap2,
                       const float* g1, const float* b1, const float* m1, const float* v1,
                       const float* g2, const float* b2, const float* m2, const float* v2,
                       float* bnp) {
  const float* __restrict__ w = blockIdx.y ? w2 : w1;
  unsigned short* __restrict__ ap = blockIdx.y ? ap2 : ap1;
  int t = blockIdx.x * 256 + threadIdx.x;   // 73728 groups per tensor
  int off = t >> 13;
  int c8  = (t >> 8) & 31;
  int co  = t & 255;
  const float* ws = w + (size_t)(co * 256 + c8 * 8) * 9 + off;
  short8 o;
#pragma unroll
  for (int j = 0; j < 8; ++j) {
    float v = ws[j * 9];
    o[j] = (v > 0.f) ? (short)0x3F80 : ((v < 0.f) ? (short)0xBF80 : (short)0);
  }
  *(short8*)(ap + (size_t)t * 8) = o;
  if (blockIdx.x == 0 && blockIdx.y == 0) {
    int c = threadIdx.x;
    float i1 = g1[c] * rsqrtf(v1[c] + EPS_F);
    bnp[c]       = SCALE_F * i1;
    bnp[256 + c] = b1[c] - m1[c] * i1;
    float i2 = g2[c] * rsqrtf(v2[c] + EPS_F);
    bnp[512 + c] = SCALE_F * i2;
    bnp[768 + c] = b2[c] - m2[c] * i2;
  }
}

// ---------------- prep kernel 2: x -> padded NHWC bf16 + border zeroing ------
// No LDS: thread = ci. Reads its private x row (float4); writes are
// 128B-contiguous across the wave (consecutive ci at fixed px).
__global__ void prep_x(const float* __restrict__ x, unsigned short* __restrict__ xb,
                       unsigned short* __restrict__ abuf) {
  int h = blockIdx.x;                // 0..27
  int n = blockIdx.y;
  int tid = threadIdx.x;             // = ci
  const float* xs = x + ((size_t)n * 256 + tid) * 784 + h * 28;
  unsigned short* xd = xb + ((size_t)n * 900 + (h + 1) * 30 + 1) * 256 + tid;
#pragma unroll
  for (int p4 = 0; p4 < 7; ++p4) {
    floatx4 f = *(const floatx4*)(xs + p4 * 4);
#pragma unroll
    for (int k = 0; k < 4; ++k)
      xd[(size_t)(p4 * 4 + k) * 256] = f2bf(f[k]);
  }
  // side borders of padded row h+1, both buffers: 2 sides * 64 c4 * 2 bufs
  {
    int bufi = tid >> 7, side = (tid >> 6) & 1, c4 = tid & 63;
    unsigned short* bb = (bufi ? abuf : xb) + ((size_t)n * 900 + (h + 1) * 30 + side * 29) * 256;
    ushort4 z = {0, 0, 0, 0};
    *(ushort4*)(bb + c4 * 4) = z;
  }
  // top/bottom padded rows
  if (h == 0 || h == 27) {
    int row = (h == 0) ? 0 : 29;
    for (int u = tid; u < 3840; u += 256) {    // 2 bufs * 30px * 64 c4
      int bufi = u / 1920;
      int r    = u - bufi * 1920;
      int px   = r >> 6, c4 = r & 63;
      unsigned short* bb = (bufi ? abuf : xb) + ((size_t)n * 900 + row * 30 + px) * 256;
      ushort4 z = {0, 0, 0, 0};
      *(ushort4*)(bb + c4 * 4) = z;
    }
  }
}

// ---------------- conv (implicit GEMM, halo-tiled) ----------------
// Block: 256 thr = 4 waves. Macro-tile: 256 co x 112 sp (4 rows) of one image.
// Wave wv: co [wv*64, +64), all 112 sp -> acc 4x7 floatx4 (AGPRs).
// ci-block 64: LDS halo 6 rows x 30 px, XOR-swizzled pitch-64; kw fully
// unrolled (3-offset scheduling window). Stage 1 epilogue goes through LDS
// for coalesced NHWC writes.
template<int STAGE>
__global__ __launch_bounds__(256, 2) void bconv(
    const unsigned short* __restrict__ Bin,
    const unsigned short* __restrict__ Apack,
    const float* __restrict__ bnp,
    unsigned short* __restrict__ aout,
    const float* __restrict__ xres,
    float* __restrict__ out)
{
  // stage 1 reuses smem for the epilogue C tile (112 px x pitch 264 ushorts)
  __shared__ __align__(16) unsigned short smem[STAGE == 1 ? 29568 : 11520];
  unsigned short* Blds = smem;

  const int tid  = threadIdx.x;
  const int lane = tid & 63;
  const int wv   = tid >> 6;
  const int quad = lane >> 4;
  const int l16  = lane & 15;
  const int spBlk = blockIdx.x;   // 0..6
  const int n     = blockIdx.y;

  const int prow0 = 4 * spBlk;
  const unsigned short* bsrc = Bin + ((size_t)n * 900 + prow0 * 30) * 256;
  const int coW = wv * 64;

  int pxS[7];
#pragma unroll
  for (int s = 0; s < 7; ++s) {
    int lm = s * 16 + l16;
    int hl = lm / 28;
    int w  = lm - hl * 28;
    pxS[s] = hl * 30 + w;
  }

  floatx4 acc[4][7];
#pragma unroll
  for (int c = 0; c < 4; ++c)
#pragma unroll
    for (int s = 0; s < 7; ++s)
      acc[c][s] = (floatx4){0.f, 0.f, 0.f, 0.f};

#pragma unroll 1
  for (int cb = 0; cb < 4; ++cb) {
    __syncthreads();   // previous ci-block's frag reads complete
    // stage 180 px x 64 ci (1440 x 16B units), swizzled
    for (int u = tid; u < 1440; u += 256) {
      int px = u >> 3, c = u & 7;
      const unsigned short* src = bsrc + (size_t)px * 256 + cb * 64 + c * 8;
      *(short8*)&Blds[(px << 6) + ((c ^ (px & 7)) << 3)] = *(const short8*)src;
    }
    __syncthreads();

    const int cq = cb * 8 + quad;
#pragma unroll 1
    for (int kh = 0; kh < 3; ++kh) {
#pragma unroll
      for (int kw = 0; kw < 3; ++kw) {
        const int D = kh * 30 + kw;
        const int chunk0 = (kh * 3 + kw) * 32 + cq;
#pragma unroll
        for (int half = 0; half < 2; ++half) {
          const int chunk = chunk0 + half * 4;
          const unsigned short* apb = Apack + ((size_t)(chunk * 256 + coW + l16)) * 8;
          short8 a0 = *(const short8*)(apb);
          short8 a1 = *(const short8*)(apb + 16 * 8);
          short8 a2 = *(const short8*)(apb + 32 * 8);
          short8 a3 = *(const short8*)(apb + 48 * 8);
          const int C = half * 4 + quad;
#pragma unroll
          for (int s = 0; s < 7; ++s) {
            int pe = pxS[s] + D;
            short8 b = *(const short8*)&Blds[(pe << 6) + ((C ^ (pe & 7)) << 3)];
            acc[0][s] = __builtin_amdgcn_mfma_f32_16x16x32_bf16(a0, b, acc[0][s], 0, 0, 0);
            acc[1][s] = __builtin_amdgcn_mfma_f32_16x16x32_bf16(a1, b, acc[1][s], 0, 0, 0);
            acc[2][s] = __builtin_amdgcn_mfma_f32_16x16x32_bf16(a2, b, acc[2][s], 0, 0, 0);
            acc[3][s] = __builtin_amdgcn_mfma_f32_16x16x32_bf16(a3, b, acc[3][s], 0, 0, 0);
          }
        }
      }
    }
  }

  // Epilogue. C/D layout: col(sp)=l16, row(co within 16-tile)=quad*4+reg.
  if (STAGE == 1) {
    // BN+ReLU -> LDS[px][co] (pitch 264), then coalesced row copies to NHWC.
    __syncthreads();   // last cb's Blds reads done before overwrite
#pragma unroll
    for (int c = 0; c < 4; ++c) {
      int co = coW + c * 16 + quad * 4;
      floatx4 As = *(const floatx4*)(bnp + co);
      floatx4 Bs = *(const floatx4*)(bnp + 256 + co);
#pragma unroll
      for (int s = 0; s < 7; ++s) {
        int px = s * 16 + l16;
        ushort4 o;
        o.x = f2bf(fmaxf(acc[c][s][0] * As[0] + Bs[0], 0.f));
        o.y = f2bf(fmaxf(acc[c][s][1] * As[1] + Bs[1], 0.f));
        o.z = f2bf(fmaxf(acc[c][s][2] * As[2] + Bs[2], 0.f));
        o.w = f2bf(fmaxf(acc[c][s][3] * As[3] + Bs[3], 0.f));
        *(ushort4*)&smem[px * 264 + co] = o;
      }
    }
    __syncthreads();
    unsigned short* dst0 = aout + ((size_t)n * 900 + (prow0 + 1) * 30 + 1) * 256;
    for (int u = tid; u < 3584; u += 256) {   // 112 px * 32 groups of 8 co
      int px = u >> 5;
      int c8 = (u & 31) * 8;
      int r  = px / 28;
      int w  = px - r * 28;
      *(short8*)(dst0 + (size_t)(r * 30 + w) * 256 + c8) = *(const short8*)&smem[px * 264 + c8];
    }
  } else {
#pragma unroll
    for (int c = 0; c < 4; ++c) {
      int co = coW + c * 16 + quad * 4;
      floatx4 As = *(const floatx4*)(bnp + 512 + co);
      floatx4 Bs = *(const floatx4*)(bnp + 768 + co);
#pragma unroll
      for (int s = 0; s < 7; ++s) {
        int m = spBlk * 112 + s * 16 + l16;
#pragma unroll
        for (int r = 0; r < 4; ++r) {
          size_t oidx = ((size_t)n * 256 + co + r) * 784 + m;
          float v = acc[c][s][r] * As[r] + Bs[r] + xres[oidx];
          out[oidx] = fmaxf(v, 0.f);
        }
      }
    }
  }
}

// ---------------- launch ----------------

extern "C" void kernel_launch(void* const* d_in, const int* in_sizes, int n_in,
                              void* d_out, int out_size, void* d_ws, size_t ws_size,
                              hipStream_t stream) {
  const float* x  = (const float*)d_in[0];
  const float* w1 = (const float*)d_in[1];
  const float* g1 = (const float*)d_in[2];
  const float* b1 = (const float*)d_in[3];
  const float* m1 = (const float*)d_in[4];
  const float* v1 = (const float*)d_in[5];
  const float* w2 = (const float*)d_in[6];
  const float* g2 = (const float*)d_in[7];
  const float* b2 = (const float*)d_in[8];
  const float* m2 = (const float*)d_in[9];
  const float* v2 = (const float*)d_in[10];
  float* out = (float*)d_out;

  char* ws = (char*)d_ws;
  const size_t PADBUF = (size_t)64 * 900 * 256 * 2;   // 29,491,200 B
  const size_t WPACK  = 589824ull * 2;                 // 1,179,648 B
  unsigned short* xb   = (unsigned short*)ws;
  unsigned short* abuf = (unsigned short*)(ws + PADBUF);
  unsigned short* ap1  = (unsigned short*)(ws + 2 * PADBUF);
  unsigned short* ap2  = (unsigned short*)(ws + 2 * PADBUF + WPACK);
  float* bnp           = (float*)(ws + 2 * PADBUF + 2 * WPACK);

  prep_w<<<dim3(288, 2), 256, 0, stream>>>(w1, w2, ap1, ap2,
                                           g1, b1, m1, v1, g2, b2, m2, v2, bnp);
  prep_x<<<dim3(28, 64), 256, 0, stream>>>(x, xb, abuf);

  dim3 grid(7, 64);   // sp-tile, image
  bconv<1><<<grid, 256, 0, stream>>>(xb,   ap1, bnp, abuf, nullptr, nullptr);
  bconv<2><<<grid, 256, 0, stream>>>(abuf, ap2, bnp, nullptr, x, out);
}